// Round 1
// baseline (268.291 us; speedup 1.0000x reference)
//
#include <hip/hip_runtime.h>

#define GROUPS 32
#define EPS 1e-5f

typedef unsigned short u16;
typedef __bf16 bf16x8 __attribute__((ext_vector_type(8)));
typedef float f32x4 __attribute__((ext_vector_type(4)));

__device__ __forceinline__ u16 f2bf(float f) {
  unsigned x = __builtin_bit_cast(unsigned, f);
  x += 0x7FFFu + ((x >> 16) & 1u);
  return (u16)(x >> 16);
}
__device__ __forceinline__ float bf2f(u16 u) {
  unsigned x = ((unsigned)u) << 16;
  return __builtin_bit_cast(float, x);
}

__device__ __forceinline__ void gload_lds16(const void* g, void* l) {
  __builtin_amdgcn_global_load_lds(
      (const __attribute__((address_space(1))) void*)g,
      (__attribute__((address_space(3))) void*)l, 16, 0, 0);
}

// ---------------- weight fp32 -> bf16 ----------------
__global__ __launch_bounds__(256) void cvt_kernel(const float* __restrict__ in,
                                                  u16* __restrict__ out, int n) {
  int i = (blockIdx.x * 256 + threadIdx.x) * 4;
  if (i < n) {
    float4 v = *(const float4*)&in[i];
    ushort4 o;
    o.x = f2bf(v.x); o.y = f2bf(v.y); o.z = f2bf(v.z); o.w = f2bf(v.w);
    *(ushort4*)&out[i] = o;
  }
}

// ---------------- GroupNorm -> HT [N, S, C] bf16 ----------------
__global__ __launch_bounds__(256) void groupnorm_kernel(
    const float* __restrict__ x, const float* __restrict__ gamma,
    const float* __restrict__ beta, u16* __restrict__ HT, int C, int S) {
  const int cpg = C / GROUPS;  // 16
  int n = blockIdx.x / GROUPS;
  int g = blockIdx.x % GROUPS;
  const float* xb = x + ((size_t)n * C + (size_t)g * cpg) * S;
  int tid = threadIdx.x;
  int cnt = cpg * S;  // 16384
  float s = 0.f, ss = 0.f;
  for (int i = tid * 4; i < cnt; i += 256 * 4) {
    float4 v = *(const float4*)&xb[i];
    s += v.x + v.y + v.z + v.w;
    ss += v.x * v.x + v.y * v.y + v.z * v.z + v.w * v.w;
  }
  for (int o = 32; o > 0; o >>= 1) {
    s += __shfl_xor(s, o);
    ss += __shfl_xor(ss, o);
  }
  __shared__ float rs[4], rss[4];
  int wave = tid >> 6, lane = tid & 63;
  if (lane == 0) { rs[wave] = s; rss[wave] = ss; }
  __syncthreads();
  float S1 = rs[0] + rs[1] + rs[2] + rs[3];
  float S2 = rss[0] + rss[1] + rss[2] + rss[3];
  float mean = S1 / (float)cnt;
  float var = S2 / (float)cnt - mean * mean;
  float rstd = rsqrtf(var + EPS);
  float gm[16], bt[16];
#pragma unroll
  for (int c = 0; c < 16; ++c) {
    float gmv = gamma[g * cpg + c] * rstd;
    gm[c] = gmv;
    bt[c] = beta[g * cpg + c] - mean * gmv;
  }
  for (int i = 0; i < S; i += 256) {
    int sp = i + tid;
    u16 outv[16];
#pragma unroll
    for (int c = 0; c < 16; ++c) {
      float h = xb[(size_t)c * S + sp] * gm[c] + bt[c];
      outv[c] = f2bf(h);
    }
    u16* dst = HT + ((size_t)n * S + sp) * C + g * cpg;
    *(int4*)dst = *(int4*)&outv[0];
    *(int4*)&dst[8] = *(int4*)&outv[8];
  }
}

// ---------------- generic bf16 GEMM, 128x128x32 tile ----------------
// A: [M, K] row-major (k contiguous), per-batch stride strideA
// B: staged as B_tile[n][k] from B + n*ldb + k (i.e. B is [N, K] row-major)
// Out[m][n] = sum_k A[m][k]*B[n][k]  (optionally *scale + bias + residual)
#define BM 128
#define BN 128
#define BK 32

__global__ __launch_bounds__(256) void gemm_kernel(
    const u16* __restrict__ A, long lda, long strideA,
    const u16* __restrict__ B, long ldb, long strideB,
    void* __restrict__ Out, long ldo, long strideO, int out_fp32,
    const float* __restrict__ bias, int bias_mode,  // 0 none, 1 row, 2 col
    float scale, const float* __restrict__ residual, int K) {
  __shared__ u16 At[BM * BK];
  __shared__ u16 Bt[BN * BK];
  int tid = threadIdx.x;
  int wave = tid >> 6, lane = tid & 63;
  int wr = wave >> 1, wc = wave & 1;
  int l15 = lane & 15, l4 = lane >> 4;
  long z = blockIdx.z;
  const u16* Ab = A + z * strideA + (long)blockIdx.y * BM * lda;
  const u16* Bb = B + z * strideB + (long)blockIdx.x * BN * ldb;

  f32x4 acc[4][4] = {};

  for (int k0 = 0; k0 < K; k0 += BK) {
    __syncthreads();  // previous tile fully consumed
#pragma unroll
    for (int i = 0; i < 2; ++i) {
      int chunk = i * 256 + tid;       // 0..511 chunks of 16B
      int row = chunk >> 2, kp = chunk & 3;
      int ldsoff = (i * 256 + wave * 64) * 8;  // elements; +lane*8 implicit
      gload_lds16(Ab + (long)row * lda + k0 + kp * 8, &At[ldsoff]);
      gload_lds16(Bb + (long)row * ldb + k0 + kp * 8, &Bt[ldsoff]);
    }
    __syncthreads();  // staging complete (vmcnt drained by barrier)
    bf16x8 af[4], bfr[4];
#pragma unroll
    for (int f = 0; f < 4; ++f) {
      af[f] = *(const bf16x8*)&At[(wr * 64 + f * 16 + l15) * BK + l4 * 8];
      bfr[f] = *(const bf16x8*)&Bt[(wc * 64 + f * 16 + l15) * BK + l4 * 8];
    }
#pragma unroll
    for (int fm = 0; fm < 4; ++fm)
#pragma unroll
      for (int fn = 0; fn < 4; ++fn)
        acc[fm][fn] = __builtin_amdgcn_mfma_f32_16x16x32_bf16(
            af[fm], bfr[fn], acc[fm][fn], 0, 0, 0);
  }

  long orow0 = (long)blockIdx.y * BM + wr * 64;
  long ocol0 = (long)blockIdx.x * BN + wc * 64;
#pragma unroll
  for (int fm = 0; fm < 4; ++fm) {
#pragma unroll
    for (int fn = 0; fn < 4; ++fn) {
#pragma unroll
      for (int r = 0; r < 4; ++r) {
        long row = orow0 + fm * 16 + l4 * 4 + r;
        long col = ocol0 + fn * 16 + l15;
        float v = acc[fm][fn][r] * scale;
        if (bias_mode == 1) v += bias[row];
        else if (bias_mode == 2) v += bias[col];
        long off = z * strideO + row * ldo + col;
        if (residual) v += residual[off];
        if (out_fp32) ((float*)Out)[off] = v;
        else ((u16*)Out)[off] = f2bf(v);
      }
    }
  }
}

// ---------------- softmax over rows of P [rows, S] bf16, in place ----------------
__global__ __launch_bounds__(256) void softmax_kernel(u16* __restrict__ P, int S) {
  size_t row = blockIdx.x;
  u16* p = P + row * (size_t)S;
  int tid = threadIdx.x;
  ushort4 u = *(const ushort4*)&p[tid * 4];
  float v0 = bf2f(u.x), v1 = bf2f(u.y), v2 = bf2f(u.z), v3 = bf2f(u.w);
  float m = fmaxf(fmaxf(v0, v1), fmaxf(v2, v3));
  for (int o = 32; o > 0; o >>= 1) m = fmaxf(m, __shfl_xor(m, o));
  __shared__ float redm[4], reds[4];
  int wave = tid >> 6, lane = tid & 63;
  if (lane == 0) redm[wave] = m;
  __syncthreads();
  m = fmaxf(fmaxf(redm[0], redm[1]), fmaxf(redm[2], redm[3]));
  float e0 = __expf(v0 - m), e1 = __expf(v1 - m);
  float e2 = __expf(v2 - m), e3 = __expf(v3 - m);
  float s = e0 + e1 + e2 + e3;
  for (int o = 32; o > 0; o >>= 1) s += __shfl_xor(s, o);
  if (lane == 0) reds[wave] = s;
  __syncthreads();
  s = reds[0] + reds[1] + reds[2] + reds[3];
  float inv = 1.f / s;
  ushort4 o4;
  o4.x = f2bf(e0 * inv); o4.y = f2bf(e1 * inv);
  o4.z = f2bf(e2 * inv); o4.w = f2bf(e3 * inv);
  *(ushort4*)&p[tid * 4] = o4;
}

extern "C" void kernel_launch(void* const* d_in, const int* in_sizes, int n_in,
                              void* d_out, int out_size, void* d_ws, size_t ws_size,
                              hipStream_t stream) {
  const float* x = (const float*)d_in[0];
  const float* gamma = (const float*)d_in[1];
  const float* beta = (const float*)d_in[2];
  const float* wq = (const float*)d_in[3];
  const float* bq = (const float*)d_in[4];
  const float* wk = (const float*)d_in[5];
  const float* bk = (const float*)d_in[6];
  const float* wv = (const float*)d_in[7];
  const float* bv = (const float*)d_in[8];
  const float* wo = (const float*)d_in[9];
  const float* bo = (const float*)d_in[10];

  const int C = 512, S = 1024;
  const int N = in_sizes[0] / (C * S);  // 16
  const long SC = (long)S * C;          // 524288
  const long SS = (long)S * S;          // 1048576
  const int CC = C * C;                 // 262144

  char* ws = (char*)d_ws;
  const size_t MB = 1024 * 1024;
  u16* HT = (u16*)(ws + 0 * MB);     // [N,S,C]
  u16* QT = (u16*)(ws + 16 * MB);    // [N,S,C]
  u16* KT = (u16*)(ws + 32 * MB);    // [N,S,C]
  u16* Vb = (u16*)(ws + 48 * MB);    // [N,C,S]
  u16* P  = (u16*)(ws + 64 * MB);    // [N,S,S]
  u16* Wq = (u16*)(ws + 96 * MB);
  u16* Wk = Wq + CC;
  u16* Wv = Wk + CC;
  u16* Wo = Wv + CC;
  u16* H2T = HT;  // overlay: HT dead after V-GEMM

  // weights to bf16
  cvt_kernel<<<CC / 1024, 256, 0, stream>>>(wq, Wq, CC);
  cvt_kernel<<<CC / 1024, 256, 0, stream>>>(wk, Wk, CC);
  cvt_kernel<<<CC / 1024, 256, 0, stream>>>(wv, Wv, CC);
  cvt_kernel<<<CC / 1024, 256, 0, stream>>>(wo, Wo, CC);

  // groupnorm -> HT [S, C] per batch
  groupnorm_kernel<<<N * GROUPS, 256, 0, stream>>>(x, gamma, beta, HT, C, S);

  const float scl = 1.0f / sqrtf((float)C);

  // QT[s][o] = sum_c HT[s][c] Wq[o][c] + bq[o]
  gemm_kernel<<<dim3(C / BN, S / BM, N), 256, 0, stream>>>(
      HT, C, SC, Wq, C, 0, QT, C, SC, 0, bq, 2, 1.f, nullptr, C);
  // KT[s][o]
  gemm_kernel<<<dim3(C / BN, S / BM, N), 256, 0, stream>>>(
      HT, C, SC, Wk, C, 0, KT, C, SC, 0, bk, 2, 1.f, nullptr, C);
  // V[o][s] = sum_c Wv[o][c] HT[s][c] + bv[o]
  gemm_kernel<<<dim3(S / BN, C / BM, N), 256, 0, stream>>>(
      Wv, C, 0, HT, C, SC, Vb, S, SC, 0, bv, 1, 1.f, nullptr, C);
  // P[s][t] = scl * sum_c QT[s][c] KT[t][c]
  gemm_kernel<<<dim3(S / BN, S / BM, N), 256, 0, stream>>>(
      QT, C, SC, KT, C, SC, P, S, SS, 0, nullptr, 0, scl, nullptr, C);
  // softmax rows of P
  softmax_kernel<<<N * S, 256, 0, stream>>>(P, S);
  // H2T[s][c] = sum_t P[s][t] V[c][t]
  gemm_kernel<<<dim3(C / BN, S / BM, N), 256, 0, stream>>>(
      P, S, SS, Vb, S, SC, H2T, C, SC, 0, nullptr, 0, 1.f, nullptr, S);
  // out[o][s] = x + bo[o] + sum_c Wo[o][c] H2T[s][c]   (fp32)
  gemm_kernel<<<dim3(S / BN, C / BM, N), 256, 0, stream>>>(
      Wo, C, 0, H2T, C, SC, d_out, S, SC, 1, bo, 1, 1.f, x, C);
}

// Round 2
// 249.305 us; speedup vs baseline: 1.0762x; 1.0762x over previous
//
#include <hip/hip_runtime.h>

#define GROUPS 32
#define EPS 1e-5f

typedef unsigned short u16;
typedef __bf16 bf16x8 __attribute__((ext_vector_type(8)));
typedef float f32x4 __attribute__((ext_vector_type(4)));

__device__ __forceinline__ u16 f2bf(float f) {
  unsigned x = __builtin_bit_cast(unsigned, f);
  x += 0x7FFFu + ((x >> 16) & 1u);
  return (u16)(x >> 16);
}
__device__ __forceinline__ float bf2f(u16 u) {
  unsigned x = ((unsigned)u) << 16;
  return __builtin_bit_cast(float, x);
}

__device__ __forceinline__ void gload_lds16(const void* g, void* l) {
  __builtin_amdgcn_global_load_lds(
      (const __attribute__((address_space(1))) void*)g,
      (__attribute__((address_space(3))) void*)l, 16, 0, 0);
}

// ---------------- weight fp32 -> bf16 (all 4 weights, one dispatch) --------
__global__ __launch_bounds__(256) void cvt_kernel(
    const float* __restrict__ wq, const float* __restrict__ wk,
    const float* __restrict__ wv, const float* __restrict__ wo,
    u16* __restrict__ Wqk, u16* __restrict__ Wv, u16* __restrict__ Wo,
    int n) {
  int i = (blockIdx.x * 256 + threadIdx.x) * 4;
  if (i >= n) return;
  const float* src;
  u16* dst;
  switch (blockIdx.y) {
    case 0: src = wq; dst = Wqk; break;
    case 1: src = wk; dst = Wqk + n; break;
    case 2: src = wv; dst = Wv; break;
    default: src = wo; dst = Wo; break;
  }
  float4 v = *(const float4*)&src[i];
  ushort4 o;
  o.x = f2bf(v.x); o.y = f2bf(v.y); o.z = f2bf(v.z); o.w = f2bf(v.w);
  *(ushort4*)&dst[i] = o;
}

// ---------------- bias concat bq||bk -> fp32[1024] ----------------
__global__ __launch_bounds__(256) void biascat_kernel(
    const float* __restrict__ bq, const float* __restrict__ bk,
    float* __restrict__ bqk, int C) {
  int i = blockIdx.x * 256 + threadIdx.x;
  if (i < C) bqk[i] = bq[i];
  else if (i < 2 * C) bqk[i] = bk[i - C];
}

// ---------------- GroupNorm -> HT [N, S, C] bf16 ----------------
__global__ __launch_bounds__(256) void groupnorm_kernel(
    const float* __restrict__ x, const float* __restrict__ gamma,
    const float* __restrict__ beta, u16* __restrict__ HT, int C, int S) {
  const int cpg = C / GROUPS;  // 16
  int n = blockIdx.x / GROUPS;
  int g = blockIdx.x % GROUPS;
  const float* xb = x + ((size_t)n * C + (size_t)g * cpg) * S;
  int tid = threadIdx.x;
  int cnt = cpg * S;  // 16384
  float s = 0.f, ss = 0.f;
  for (int i = tid * 4; i < cnt; i += 256 * 4) {
    float4 v = *(const float4*)&xb[i];
    s += v.x + v.y + v.z + v.w;
    ss += v.x * v.x + v.y * v.y + v.z * v.z + v.w * v.w;
  }
  for (int o = 32; o > 0; o >>= 1) {
    s += __shfl_xor(s, o);
    ss += __shfl_xor(ss, o);
  }
  __shared__ float rs[4], rss[4];
  int wave = tid >> 6, lane = tid & 63;
  if (lane == 0) { rs[wave] = s; rss[wave] = ss; }
  __syncthreads();
  float S1 = rs[0] + rs[1] + rs[2] + rs[3];
  float S2 = rss[0] + rss[1] + rss[2] + rss[3];
  float mean = S1 / (float)cnt;
  float var = S2 / (float)cnt - mean * mean;
  float rstd = rsqrtf(var + EPS);
  float gm[16], bt[16];
#pragma unroll
  for (int c = 0; c < 16; ++c) {
    float gmv = gamma[g * cpg + c] * rstd;
    gm[c] = gmv;
    bt[c] = beta[g * cpg + c] - mean * gmv;
  }
  for (int i = 0; i < S; i += 256) {
    int sp = i + tid;
    u16 outv[16];
#pragma unroll
    for (int c = 0; c < 16; ++c) {
      float h = xb[(size_t)c * S + sp] * gm[c] + bt[c];
      outv[c] = f2bf(h);
    }
    u16* dst = HT + ((size_t)n * S + sp) * C + g * cpg;
    *(int4*)dst = *(int4*)&outv[0];
    *(int4*)&dst[8] = *(int4*)&outv[8];
  }
}

// ---------------- pipelined bf16 GEMM, 128x128x32, depth-2 prefetch -------
// Out[m][n] = scale * sum_k A[m][k]*B[n][k]  (+bias/residual)
// 3-buffer LDS, 1 raw s_barrier per K-step, counted vmcnt(4).
// LDS chunk swizzle: 16B slot c holds global chunk c ^ ((row>>1)&3)
// (pre-swizzled global source, swizzled read -> 2-way banks, conflict-free).
#define BM 128
#define BN 128
#define BK 32
#define NBUF 3

__global__ __launch_bounds__(256) void gemm_kernel(
    const u16* __restrict__ A, long lda, long strideA,
    const u16* __restrict__ B, long ldb, long strideB,
    void* __restrict__ Out, long ldo, long strideO, int out_fp32,
    const float* __restrict__ bias, int bias_mode,  // 0 none, 1 row, 2 col
    float scale, const float* __restrict__ residual, int K) {
  __shared__ u16 At[NBUF][BM * BK];
  __shared__ u16 Bt[NBUF][BN * BK];
  int tid = threadIdx.x;
  int wave = tid >> 6, lane = tid & 63;
  int wr = wave >> 1, wc = wave & 1;
  int l15 = lane & 15, l4 = lane >> 4;
  long z = blockIdx.z;
  const u16* Ab = A + z * strideA + (long)blockIdx.y * BM * lda;
  const u16* Bb = B + z * strideB + (long)blockIdx.x * BN * ldb;

  auto STAGE = [&](int bufi, int k0) {
    u16* Adst = &At[bufi][0];
    u16* Bdst = &Bt[bufi][0];
#pragma unroll
    for (int i = 0; i < 2; ++i) {
      int c = i * 256 + tid;
      int row = c >> 2, kp = c & 3;
      int kpg = kp ^ ((row >> 1) & 3);           // inverse swizzle on source
      int lbase = (i * 256 + wave * 64) * 8;     // wave-uniform LDS base
      gload_lds16(Ab + (long)row * lda + k0 + kpg * 8, Adst + lbase);
      gload_lds16(Bb + (long)row * ldb + k0 + kpg * 8, Bdst + lbase);
    }
  };

  f32x4 acc[4][4] = {};
  int NT = K >> 5;
  STAGE(0, 0);
  STAGE(1, BK);

  for (int t = 0; t < NT; ++t) {
    if (t + 1 < NT) {
      asm volatile("s_waitcnt vmcnt(4)" ::: "memory");   // own stage(t) done
    } else {
      asm volatile("s_waitcnt vmcnt(0)" ::: "memory");   // last tile: drain
    }
    __builtin_amdgcn_sched_barrier(0);
    __builtin_amdgcn_s_barrier();                        // all waves' stage(t) done
    __builtin_amdgcn_sched_barrier(0);
    if (t + 2 < NT) STAGE((t + 2) % NBUF, (t + 2) * BK);

    const u16* Asrc = &At[t % NBUF][0];
    const u16* Bsrc = &Bt[t % NBUF][0];
    bf16x8 af[4], bfr[4];
#pragma unroll
    for (int f = 0; f < 4; ++f) {
      int ra = wr * 64 + f * 16 + l15;
      int rb = wc * 64 + f * 16 + l15;
      int sa = l4 ^ ((ra >> 1) & 3);                     // swizzled read slot
      int sb = l4 ^ ((rb >> 1) & 3);
      af[f] = *(const bf16x8*)&Asrc[ra * BK + sa * 8];
      bfr[f] = *(const bf16x8*)&Bsrc[rb * BK + sb * 8];
    }
    asm volatile("s_waitcnt lgkmcnt(0)" ::: "memory");
    __builtin_amdgcn_sched_barrier(0);
    __builtin_amdgcn_s_setprio(1);
#pragma unroll
    for (int fm = 0; fm < 4; ++fm)
#pragma unroll
      for (int fn = 0; fn < 4; ++fn)
        acc[fm][fn] = __builtin_amdgcn_mfma_f32_16x16x32_bf16(
            af[fm], bfr[fn], acc[fm][fn], 0, 0, 0);
    __builtin_amdgcn_s_setprio(0);
  }

  long orow0 = (long)blockIdx.y * BM + wr * 64;
  long ocol0 = (long)blockIdx.x * BN + wc * 64;
#pragma unroll
  for (int fm = 0; fm < 4; ++fm) {
#pragma unroll
    for (int fn = 0; fn < 4; ++fn) {
#pragma unroll
      for (int r = 0; r < 4; ++r) {
        long row = orow0 + fm * 16 + l4 * 4 + r;
        long col = ocol0 + fn * 16 + l15;
        float v = acc[fm][fn][r] * scale;
        if (bias_mode == 1) v += bias[row];
        else if (bias_mode == 2) v += bias[col];
        long off = z * strideO + row * ldo + col;
        if (residual) v += residual[off];
        if (out_fp32) ((float*)Out)[off] = v;
        else ((u16*)Out)[off] = f2bf(v);
      }
    }
  }
}

// ---------------- softmax over rows of P [rows, S] bf16, in place ----------
__global__ __launch_bounds__(256) void softmax_kernel(u16* __restrict__ P, int S) {
  size_t row = blockIdx.x;
  u16* p = P + row * (size_t)S;
  int tid = threadIdx.x;
  ushort4 u = *(const ushort4*)&p[tid * 4];
  float v0 = bf2f(u.x), v1 = bf2f(u.y), v2 = bf2f(u.z), v3 = bf2f(u.w);
  float m = fmaxf(fmaxf(v0, v1), fmaxf(v2, v3));
  for (int o = 32; o > 0; o >>= 1) m = fmaxf(m, __shfl_xor(m, o));
  __shared__ float redm[4], reds[4];
  int wave = tid >> 6, lane = tid & 63;
  if (lane == 0) redm[wave] = m;
  __syncthreads();
  m = fmaxf(fmaxf(redm[0], redm[1]), fmaxf(redm[2], redm[3]));
  float e0 = __expf(v0 - m), e1 = __expf(v1 - m);
  float e2 = __expf(v2 - m), e3 = __expf(v3 - m);
  float s = e0 + e1 + e2 + e3;
  for (int o = 32; o > 0; o >>= 1) s += __shfl_xor(s, o);
  if (lane == 0) reds[wave] = s;
  __syncthreads();
  s = reds[0] + reds[1] + reds[2] + reds[3];
  float inv = 1.f / s;
  ushort4 o4;
  o4.x = f2bf(e0 * inv); o4.y = f2bf(e1 * inv);
  o4.z = f2bf(e2 * inv); o4.w = f2bf(e3 * inv);
  *(ushort4*)&p[tid * 4] = o4;
}

extern "C" void kernel_launch(void* const* d_in, const int* in_sizes, int n_in,
                              void* d_out, int out_size, void* d_ws, size_t ws_size,
                              hipStream_t stream) {
  const float* x = (const float*)d_in[0];
  const float* gamma = (const float*)d_in[1];
  const float* beta = (const float*)d_in[2];
  const float* wq = (const float*)d_in[3];
  const float* bq = (const float*)d_in[4];
  const float* wk = (const float*)d_in[5];
  const float* bk = (const float*)d_in[6];
  const float* wv = (const float*)d_in[7];
  const float* bv = (const float*)d_in[8];
  const float* wo = (const float*)d_in[9];
  const float* bo = (const float*)d_in[10];

  const int C = 512, S = 1024;
  const int N = in_sizes[0] / (C * S);  // 16
  const long SC = (long)S * C;          // 524288
  const long S2C = (long)S * 2 * C;     // 1048576 (QK concat row stride*S)
  const long SS = (long)S * S;
  const int CC = C * C;

  char* ws = (char*)d_ws;
  const size_t MB = 1024 * 1024;
  u16* HT = (u16*)(ws + 0 * MB);      // [N,S,C]
  u16* QKT = (u16*)(ws + 16 * MB);    // [N,S,2C]: cols 0..C-1 = Q, C..2C-1 = K
  u16* Vb = (u16*)(ws + 48 * MB);     // [N,C,S]
  u16* P = (u16*)(ws + 64 * MB);      // [N,S,S]
  u16* Wqk = (u16*)(ws + 96 * MB);    // [2C,C]
  u16* Wv = Wqk + 2 * CC;
  u16* Wo = Wv + CC;
  float* bqk = (float*)(Wo + CC);     // [2C]
  u16* H2T = HT;                      // overlay: HT dead after V-GEMM

  cvt_kernel<<<dim3(CC / 1024, 4), 256, 0, stream>>>(wq, wk, wv, wo, Wqk, Wv, Wo, CC);
  biascat_kernel<<<4, 256, 0, stream>>>(bq, bk, bqk, C);
  groupnorm_kernel<<<N * GROUPS, 256, 0, stream>>>(x, gamma, beta, HT, C, S);

  const float scl = 1.0f / sqrtf((float)C);

  // fused Q,K projection: QKT[s][j] = sum_c HT[s][c]*Wqk[j][c] + bqk[j]
  gemm_kernel<<<dim3(2 * C / BN, S / BM, N), 256, 0, stream>>>(
      HT, C, SC, Wqk, C, 0, QKT, 2 * C, S2C, 0, bqk, 2, 1.f, nullptr, C);
  // V[o][s] = sum_c Wv[o][c]*HT[s][c] + bv[o]
  gemm_kernel<<<dim3(S / BN, C / BM, N), 256, 0, stream>>>(
      Wv, C, 0, HT, C, SC, Vb, S, SC, 0, bv, 1, 1.f, nullptr, C);
  // P[s][t] = scl * sum_c Q[s][c]*K[t][c]
  gemm_kernel<<<dim3(S / BN, S / BM, N), 256, 0, stream>>>(
      QKT, 2 * C, S2C, QKT + C, 2 * C, S2C, P, S, SS, 0, nullptr, 0, scl, nullptr, C);
  softmax_kernel<<<N * S, 256, 0, stream>>>(P, S);
  // H2T[s][c] = sum_t P[s][t]*V[c][t]
  gemm_kernel<<<dim3(C / BN, S / BM, N), 256, 0, stream>>>(
      P, S, SS, Vb, S, SC, H2T, C, SC, 0, nullptr, 0, 1.f, nullptr, S);
  // out[o][s] = x + bo[o] + sum_c Wo[o][c]*H2T[s][c]   (fp32)
  gemm_kernel<<<dim3(S / BN, C / BM, N), 256, 0, stream>>>(
      Wo, C, 0, H2T, C, SC, d_out, S, SC, 1, bo, 1, 1.f, x, C);
}